// Round 12
// baseline (298.173 us; speedup 1.0000x reference)
//
#include <hip/hip_runtime.h>
#include <hip/hip_bf16.h>

#define NH 24
#define HD 128
#define DM 3072
#define NB 2
#define SN 256
#define MR 512            // NB*SN rows
#define SCACHE 8192
#define NCH 9             // 6 chunks of 15 tiles + 3 of 14 tiles (132 tiles of 64 keys)

typedef float f32x4 __attribute__((ext_vector_type(4)));
typedef float f32x2 __attribute__((ext_vector_type(2)));
typedef short s16x8 __attribute__((ext_vector_type(8)));
typedef short s16x4 __attribute__((ext_vector_type(4)));
typedef unsigned u32x4 __attribute__((ext_vector_type(4)));

__device__ __forceinline__ short bfc(float f) {
    __hip_bfloat16 h = __float2bfloat16(f);
    return __builtin_bit_cast(short, h);
}

// ---------------- x -> bf16 (one-time cast) ----------------
__global__ __launch_bounds__(256) void xcast(const float* __restrict__ src, short* __restrict__ dst)
{
    const int i = (blockIdx.x * 256 + threadIdx.x) * 8;
    f32x4 a = *(const f32x4*)(src + i);
    f32x4 b = *(const f32x4*)(src + i + 4);
    s16x8 o;
    #pragma unroll
    for (int j = 0; j < 4; ++j) { o[j] = bfc(a[j]); o[4 + j] = bfc(b[j]); }
    *(s16x8*)(dst + i) = o;
}

// ---------------- GEMM: O[m,n] = sum_k A[m,k]*W[n,k] + bias[n] (bf16 A) ----------------
__global__ __launch_bounds__(256, 3) void gemm_bias(
    const short* __restrict__ A,
    const float* __restrict__ W0, const float* __restrict__ W1, const float* __restrict__ W2,
    const float* __restrict__ b0, const float* __restrict__ b1, const float* __restrict__ b2,
    float* __restrict__ O0, float* __restrict__ O1, float* __restrict__ O2)
{
    const int z = blockIdx.z;
    const float* W    = (z == 0) ? W0 : (z == 1) ? W1 : W2;
    const float* bias = (z == 0) ? b0 : (z == 1) ? b1 : b2;
    float* O          = (z == 0) ? O0 : (z == 1) ? O1 : O2;

    const int n0 = blockIdx.x * 64;
    const int m0 = blockIdx.y * 128;
    const int t = threadIdx.x;
    const int lane = t & 63;
    const int wave = t >> 6;
    const int l15 = lane & 15, l4 = lane >> 4;
    const int wm = wave * 32;

    __shared__ short As[128][72];
    __shared__ short Bs[64][72];

    f32x4 acc[2][4] = {};
    s16x8 areg[4];
    f32x4 breg[4];

    #pragma unroll
    for (int i = 0; i < 4; ++i) {
        int lin = i * 256 + t;
        areg[i] = *(const s16x8*)(A + (size_t)(m0 + (lin >> 3)) * DM + (lin & 7) * 8);
    }
    #pragma unroll
    for (int i = 0; i < 4; ++i) {
        int lin = i * 256 + t;
        breg[i] = *(const f32x4*)(W + (size_t)(n0 + (lin >> 4)) * DM + (lin & 15) * 4);
    }

    for (int ks = 0; ks < DM / 64; ++ks) {
        #pragma unroll
        for (int i = 0; i < 4; ++i) {
            int lin = i * 256 + t;
            *(s16x8*)&As[lin >> 3][(lin & 7) * 8] = areg[i];
        }
        #pragma unroll
        for (int i = 0; i < 4; ++i) {
            int lin = i * 256 + t;
            s16x4 w4;
            #pragma unroll
            for (int j = 0; j < 4; ++j) w4[j] = bfc(breg[i][j]);
            *(s16x4*)&Bs[lin >> 4][(lin & 15) * 4] = w4;
        }
        __syncthreads();
        if (ks + 1 < DM / 64) {
            int k0 = (ks + 1) * 64;
            #pragma unroll
            for (int i = 0; i < 4; ++i) {
                int lin = i * 256 + t;
                areg[i] = *(const s16x8*)(A + (size_t)(m0 + (lin >> 3)) * DM + k0 + (lin & 7) * 8);
            }
            #pragma unroll
            for (int i = 0; i < 4; ++i) {
                int lin = i * 256 + t;
                breg[i] = *(const f32x4*)(W + (size_t)(n0 + (lin >> 4)) * DM + k0 + (lin & 15) * 4);
            }
        }
        #pragma unroll
        for (int kt = 0; kt < 2; ++kt) {
            s16x8 af[2], bfr[4];
            #pragma unroll
            for (int i = 0; i < 2; ++i)
                af[i]  = *(const s16x8*)&As[wm + i * 16 + l15][kt * 32 + l4 * 8];
            #pragma unroll
            for (int i = 0; i < 4; ++i)
                bfr[i] = *(const s16x8*)&Bs[i * 16 + l15][kt * 32 + l4 * 8];
            #pragma unroll
            for (int mi = 0; mi < 2; ++mi)
                #pragma unroll
                for (int ni = 0; ni < 4; ++ni)
                    acc[mi][ni] = __builtin_amdgcn_mfma_f32_16x16x32_bf16(
                        af[mi], bfr[ni], acc[mi][ni], 0, 0, 0);
        }
        __syncthreads();
    }

    #pragma unroll
    for (int ni = 0; ni < 4; ++ni) {
        int col = n0 + ni * 16 + l15;
        float bv = bias[col];
        #pragma unroll
        for (int mi = 0; mi < 2; ++mi) {
            int row = m0 + wm + mi * 16 + l4 * 4;
            #pragma unroll
            for (int r = 0; r < 4; ++r)
                O[(size_t)(row + r) * DM + col] = acc[mi][ni][r] + bv;
        }
    }
}

// ---------------- RMSNorm + RoPE; Q pre-scaled by 1/sqrt(128)*log2e -> bf16 ----------------
__global__ __launch_bounds__(256) void norm_rope(
    float* __restrict__ qf, float* __restrict__ kf, short* __restrict__ qbf,
    const float* __restrict__ gq, const float* __restrict__ gk,
    const float* __restrict__ freqs)
{
    const int buf = blockIdx.x >> 9;
    const int row = blockIdx.x & 511;
    const int t = threadIdx.x;
    float* src = buf ? kf : qf;
    const float* g = buf ? gk : gq;

    f32x2 v[6];
    float ss = 0.f;
    #pragma unroll
    for (int i = 0; i < 6; ++i) {
        int p = t + 256 * i;
        v[i] = *(const f32x2*)(src + (size_t)row * DM + 2 * p);
        ss += v[i][0] * v[i][0] + v[i][1] * v[i][1];
    }
    #pragma unroll
    for (int m = 1; m < 64; m <<= 1) ss += __shfl_xor(ss, m);
    __shared__ float red[4];
    if ((t & 63) == 0) red[t >> 6] = ss;
    __syncthreads();
    ss = red[0] + red[1] + red[2] + red[3];
    const float scale = rsqrtf(ss * (1.0f / DM) + 1e-6f);
    const float QS = 0.08838834764831845f * 1.4426950408889634f; // 1/sqrt(128)*log2e

    const int spos = row & 255;
    #pragma unroll
    for (int i = 0; i < 6; ++i) {
        int p = t + 256 * i;
        int d2 = p & 63;
        float fr = freqs[spos * 64 + d2];
        float snv, cs;
        __sincosf(fr, &snv, &cs);
        f32x2 gg = *(const f32x2*)(g + 2 * p);
        float re = v[i][0] * scale * gg[0];
        float im = v[i][1] * scale * gg[1];
        float re2 = re * cs - im * snv;
        float im2 = re * snv + im * cs;
        if (buf == 0) {
            re2 *= QS; im2 *= QS;
            unsigned pack = (unsigned)(unsigned short)bfc(re2)
                          | ((unsigned)(unsigned short)bfc(im2) << 16);
            *(unsigned*)(qbf + (size_t)row * DM + 2 * p) = pack;
        } else {
            f32x2 o; o[0] = re2; o[1] = im2;
            *(f32x2*)(src + (size_t)row * DM + 2 * p) = o;
        }
    }
}

// ---------------- Flash attention: swapped QK^T, in-reg P, dbuf LDS, lazy softmax,
// ones-row-L, wide LDS staging (b128 K / b32-pair V), setprio MFMA clusters ----------------
__global__ __launch_bounds__(512, 2) void attn_fa(
    const short* __restrict__ qbf,
    const float* __restrict__ kf, const float* __restrict__ vf,
    const float* __restrict__ kcache, const float* __restrict__ vcache,
    short* __restrict__ partO, float* __restrict__ partM, float* __restrict__ partL)
{
    const int bid = blockIdx.x;               // 0..431
    const int linear = (bid & 7) * 54 + (bid >> 3);
    const int c  = linear / 48;
    const int bh = linear % 48;
    const int b = bh / NH, h = bh % NH;
    const int t = threadIdx.x, lane = t & 63, wave = t >> 6;
    const int l15 = lane & 15, l4 = lane >> 4;
    const int hoff = h * HD;

    __shared__ short KsA[2][64 * 128];   // [k][d] 256B rows, chunk-swizzled
    __shared__ short VtA[2][128 * 64];   // [d][k] 128B rows, chunk-swizzled

    // Q B-fragments
    s16x8 qb[2][4];
    #pragma unroll
    for (int nj = 0; nj < 2; ++nj) {
        int qrow = b * SN + wave * 32 + nj * 16 + l15;
        #pragma unroll
        for (int kt = 0; kt < 4; ++kt)
            qb[nj][kt] = *(const s16x8*)(qbf + (size_t)qrow * DM + hoff + kt * 32 + l4 * 8);
    }

    f32x4 acc[2][8] = {};
    f32x4 accL[2] = {};                  // ones-row PV -> per-q softmax denominator
    float mrun[2] = {-INFINITY, -INFINITY};

    s16x8 ones1;
    #pragma unroll
    for (int j = 0; j < 8; ++j) ones1[j] = (short)0x3F80;   // bf16 1.0

    const int ts = (c < 6) ? c * 15 : 90 + (c - 6) * 14;
    const int NT = (c < 6) ? 15 : 14;

    const float* kcB = kcache + (size_t)b * SCACHE * DM + hoff;
    const float* knB = kf     + (size_t)b * SN * DM + hoff;
    const float* vcB = vcache + (size_t)b * SCACHE * DM + hoff;
    const float* vnB = vf     + (size_t)b * SN * DM + hoff;

    // staging coords: K thread -> (row, 64B slice); V thread -> (key-pair, 8 d)
    const int krow = t >> 3, kcb = (t & 7) * 2;      // K: 8 thr/row, 2 chunks each
    const int vk0 = (t & 31) * 2, vdb = (t >> 5) * 8;
    f32x4 kreg[4], vreg[4];

    // prologue: tile 0 loads (base hoisted, wave-uniform select)
    {
        const int kr = ts * 64;
        const float* kb; const float* vb;
        if (kr < SCACHE) { kb = kcB + (size_t)kr * DM; vb = vcB + (size_t)kr * DM; }
        else             { kb = knB + (size_t)(kr - SCACHE) * DM; vb = vnB + (size_t)(kr - SCACHE) * DM; }
        #pragma unroll
        for (int i = 0; i < 4; ++i)
            kreg[i] = *(const f32x4*)(kb + (size_t)krow * DM + kcb * 8 + i * 4);
        vreg[0] = *(const f32x4*)(vb + (size_t)vk0 * DM + vdb);
        vreg[1] = *(const f32x4*)(vb + (size_t)vk0 * DM + vdb + 4);
        vreg[2] = *(const f32x4*)(vb + (size_t)(vk0 + 1) * DM + vdb);
        vreg[3] = *(const f32x4*)(vb + (size_t)(vk0 + 1) * DM + vdb + 4);
    }

    const bool ghi = (l4 & 2) != 0;
    const bool gin = (l4 == 0) || (l4 == 3);

    for (int nt = 0; nt < NT; ++nt) {
        char* KsB = (char*)KsA[nt & 1];
        char* VtB = (char*)VtA[nt & 1];

        // ---- stage regs -> LDS buf[nt&1] (chunk-swizzled, wide writes) ----
        {
            s16x8 h0, h1;
            #pragma unroll
            for (int j = 0; j < 4; ++j) {
                h0[j] = bfc(kreg[0][j]); h0[4 + j] = bfc(kreg[1][j]);
                h1[j] = bfc(kreg[2][j]); h1[4 + j] = bfc(kreg[3][j]);
            }
            *(s16x8*)(KsB + (krow << 8) + (((kcb    ) ^ (krow & 15)) << 4)) = h0;
            *(s16x8*)(KsB + (krow << 8) + (((kcb + 1) ^ (krow & 15)) << 4)) = h1;
        }
        #pragma unroll
        for (int jj = 0; jj < 8; ++jj) {
            int d = vdb + jj;
            unsigned pk = (unsigned)(unsigned short)bfc(vreg[jj >> 2][jj & 3])
                        | ((unsigned)(unsigned short)bfc(vreg[2 + (jj >> 2)][jj & 3]) << 16);
            *(unsigned*)(VtB + (d << 7) + ((((vk0 >> 3) ^ (d & 7))) << 4) + ((vk0 & 7) << 1)) = pk;
        }
        __syncthreads();   // single barrier per tile (double-buffered)

        // ---- issue next-tile loads (fly across all compute) ----
        if (nt + 1 < NT) {
            const int kr1 = (ts + nt + 1) * 64;
            const float* kb; const float* vb;
            if (kr1 < SCACHE) { kb = kcB + (size_t)kr1 * DM; vb = vcB + (size_t)kr1 * DM; }
            else              { kb = knB + (size_t)(kr1 - SCACHE) * DM; vb = vnB + (size_t)(kr1 - SCACHE) * DM; }
            #pragma unroll
            for (int i = 0; i < 4; ++i)
                kreg[i] = *(const f32x4*)(kb + (size_t)krow * DM + kcb * 8 + i * 4);
            vreg[0] = *(const f32x4*)(vb + (size_t)vk0 * DM + vdb);
            vreg[1] = *(const f32x4*)(vb + (size_t)vk0 * DM + vdb + 4);
            vreg[2] = *(const f32x4*)(vb + (size_t)(vk0 + 1) * DM + vdb);
            vreg[3] = *(const f32x4*)(vb + (size_t)(vk0 + 1) * DM + vdb + 4);
        }

        // ---- S^T = K * Q^T ----
        f32x4 st[4][2] = {};
        __builtin_amdgcn_s_setprio(1);
        #pragma unroll
        for (int kt = 0; kt < 4; ++kt)
            #pragma unroll
            for (int mi = 0; mi < 4; ++mi) {
                int row = mi * 16 + l15;
                s16x8 kfr = *(const s16x8*)(KsB + (row << 8) + (((kt * 4 + l4) ^ l15) << 4));
                st[mi][0] = __builtin_amdgcn_mfma_f32_16x16x32_bf16(kfr, qb[0][kt], st[mi][0], 0, 0, 0);
                st[mi][1] = __builtin_amdgcn_mfma_f32_16x16x32_bf16(kfr, qb[1][kt], st[mi][1], 0, 0, 0);
            }
        __builtin_amdgcn_s_setprio(0);

        // ---- online softmax: max3-grouped in-lane tree, lazy cross-lane ----
        float a0 = fmaxf(fmaxf(st[0][0][0], st[0][0][1]), st[0][0][2]);
        float a1 = fmaxf(fmaxf(st[0][0][3], st[1][0][0]), st[1][0][1]);
        float a2 = fmaxf(fmaxf(st[1][0][2], st[1][0][3]), st[2][0][0]);
        float a3 = fmaxf(fmaxf(st[2][0][1], st[2][0][2]), st[2][0][3]);
        float a4 = fmaxf(fmaxf(st[3][0][0], st[3][0][1]), st[3][0][2]);
        float lx0 = fmaxf(fmaxf(fmaxf(a0, a1), a2), fmaxf(fmaxf(a3, a4), st[3][0][3]));
        float b0_ = fmaxf(fmaxf(st[0][1][0], st[0][1][1]), st[0][1][2]);
        float b1_ = fmaxf(fmaxf(st[0][1][3], st[1][1][0]), st[1][1][1]);
        float b2_ = fmaxf(fmaxf(st[1][1][2], st[1][1][3]), st[2][1][0]);
        float b3_ = fmaxf(fmaxf(st[2][1][1], st[2][1][2]), st[2][1][3]);
        float b4_ = fmaxf(fmaxf(st[3][1][0], st[3][1][1]), st[3][1][2]);
        float lx1 = fmaxf(fmaxf(fmaxf(b0_, b1_), b2_), fmaxf(fmaxf(b3_, b4_), st[3][1][3]));

        if (!__all((lx0 <= mrun[0] + 8.0f) && (lx1 <= mrun[1] + 8.0f))) {
            float lm0 = fmaxf(lx0, __shfl_xor(lx0, 16)); lm0 = fmaxf(lm0, __shfl_xor(lm0, 32));
            float lm1 = fmaxf(lx1, __shfl_xor(lx1, 16)); lm1 = fmaxf(lm1, __shfl_xor(lm1, 32));
            float mn0 = fmaxf(mrun[0], lm0), mn1 = fmaxf(mrun[1], lm1);
            float c0 = exp2f(mrun[0] - mn0), c1 = exp2f(mrun[1] - mn1);
            mrun[0] = mn0; mrun[1] = mn1;
            accL[0] *= c0; accL[1] *= c1;
            #pragma unroll
            for (int df = 0; df < 8; ++df) { acc[0][df] *= c0; acc[1][df] *= c1; }
        }

        #pragma unroll
        for (int mi = 0; mi < 4; ++mi)
            #pragma unroll
            for (int r = 0; r < 4; ++r) {
                st[mi][0][r] = exp2f(st[mi][0][r] - mrun[0]);
                st[mi][1][r] = exp2f(st[mi][1][r] - mrun[1]);
            }

        // ---- pack P to bf16 pairs ----
        unsigned up[2][4][2];
        #pragma unroll
        for (int nj = 0; nj < 2; ++nj)
            #pragma unroll
            for (int mi = 0; mi < 4; ++mi)
                #pragma unroll
                for (int i = 0; i < 2; ++i)
                    up[nj][mi][i] = (unsigned)(unsigned short)bfc(st[mi][nj][2 * i])
                                  | ((unsigned)(unsigned short)bfc(st[mi][nj][2 * i + 1]) << 16);

        // ---- cross-group exchange -> PV B-frags ----
        s16x8 bp[2][2];
        #pragma unroll
        for (int nj = 0; nj < 2; ++nj)
            #pragma unroll
            for (int kt2 = 0; kt2 < 2; ++kt2) {
                unsigned own0 = ghi ? up[nj][kt2 * 2 + 1][0] : up[nj][kt2 * 2 + 0][0];
                unsigned own1 = ghi ? up[nj][kt2 * 2 + 1][1] : up[nj][kt2 * 2 + 0][1];
                unsigned alt0 = ghi ? up[nj][kt2 * 2 + 0][0] : up[nj][kt2 * 2 + 1][0];
                unsigned alt1 = ghi ? up[nj][kt2 * 2 + 0][1] : up[nj][kt2 * 2 + 1][1];
                unsigned o16_0 = __shfl_xor(own0, 16), o16_1 = __shfl_xor(own1, 16);
                unsigned o32_0 = __shfl_xor(alt0, 32), o32_1 = __shfl_xor(alt1, 32);
                unsigned o48_0 = __shfl_xor(alt0, 48), o48_1 = __shfl_xor(alt1, 48);
                u32x4 uu;
                uu[0] = gin ? (ghi ? o16_0 : own0) : (ghi ? o32_0 : o48_0);
                uu[1] = gin ? (ghi ? o16_1 : own1) : (ghi ? o32_1 : o48_1);
                uu[2] = gin ? (ghi ? own0 : o16_0) : (ghi ? o48_0 : o32_0);
                uu[3] = gin ? (ghi ? own1 : o16_1) : (ghi ? o48_1 : o32_1);
                bp[nj][kt2] = __builtin_bit_cast(s16x8, uu);
            }

        // ---- PV (+ ones-row for L) ----
        __builtin_amdgcn_s_setprio(1);
        #pragma unroll
        for (int kt2 = 0; kt2 < 2; ++kt2) {
            #pragma unroll
            for (int df = 0; df < 8; ++df) {
                int row = df * 16 + l15;
                s16x8 vfr = *(const s16x8*)(VtB + (row << 7) + (((kt2 * 4 + l4) ^ (row & 7)) << 4));
                acc[0][df] = __builtin_amdgcn_mfma_f32_16x16x32_bf16(vfr, bp[0][kt2], acc[0][df], 0, 0, 0);
                acc[1][df] = __builtin_amdgcn_mfma_f32_16x16x32_bf16(vfr, bp[1][kt2], acc[1][df], 0, 0, 0);
            }
            accL[0] = __builtin_amdgcn_mfma_f32_16x16x32_bf16(ones1, bp[0][kt2], accL[0], 0, 0, 0);
            accL[1] = __builtin_amdgcn_mfma_f32_16x16x32_bf16(ones1, bp[1][kt2], accL[1], 0, 0, 0);
        }
        __builtin_amdgcn_s_setprio(0);
    }

    // ---- write partials (bf16 O; L directly from accL) ----
    #pragma unroll
    for (int nj = 0; nj < 2; ++nj) {
        size_t rowid = (size_t)bh * SN + wave * 32 + nj * 16 + l15;
        short* po = partO + (rowid * NCH + c) * HD + l4 * 4;
        #pragma unroll
        for (int df = 0; df < 8; ++df) {
            s16x4 ob;
            #pragma unroll
            for (int r = 0; r < 4; ++r) ob[r] = bfc(acc[nj][df][r]);
            *(s16x4*)(po + df * 16) = ob;
        }
        if (l4 == 0) {
            partM[rowid * NCH + c] = mrun[nj];
            partL[rowid * NCH + c] = accL[nj][0];
        }
    }
}

// ---------------- combine split-K partials (bf16 partO -> bf16 attn) ----------------
__global__ __launch_bounds__(128) void combine(
    const short* __restrict__ partO, const float* __restrict__ partM,
    const float* __restrict__ partL, short* __restrict__ attnb)
{
    const int rowid = blockIdx.x;        // bh*256 + q
    const int bh = rowid >> 8, q = rowid & 255;
    const int b = bh / NH, h = bh % NH;
    const int d = threadIdx.x;

    float m[NCH];
    float M = -INFINITY;
    #pragma unroll
    for (int c = 0; c < NCH; ++c) { m[c] = partM[(size_t)rowid * NCH + c]; M = fmaxf(M, m[c]); }
    float L = 0.f, o = 0.f;
    #pragma unroll
    for (int c = 0; c < NCH; ++c) {
        float w = exp2f(m[c] - M);
        L += partL[(size_t)rowid * NCH + c] * w;
        unsigned ub = (unsigned)(unsigned short)partO[((size_t)rowid * NCH + c) * HD + d];
        float ov = __builtin_bit_cast(float, ub << 16);
        o += ov * w;
    }
    attnb[(size_t)(b * SN + q) * DM + h * HD + d] = bfc(o / L);
}

extern "C" void kernel_launch(void* const* d_in, const int* in_sizes, int n_in,
                              void* d_out, int out_size, void* d_ws, size_t ws_size,
                              hipStream_t stream) {
    const float* x      = (const float*)d_in[0];
    const float* freqs  = (const float*)d_in[1];
    const float* kcache = (const float*)d_in[2];
    const float* vcache = (const float*)d_in[3];
    const float* Wq = (const float*)d_in[4];
    const float* bq = (const float*)d_in[5];
    const float* Wk = (const float*)d_in[6];
    const float* bk = (const float*)d_in[7];
    const float* Wv = (const float*)d_in[8];
    const float* bv = (const float*)d_in[9];
    const float* Wo = (const float*)d_in[10];
    const float* bo = (const float*)d_in[11];
    const float* gq = (const float*)d_in[12];
    const float* gk = (const float*)d_in[13];
    float* out = (float*)d_out;

    auto al = [](size_t v) { return (v + 255) & ~(size_t)255; };
    const size_t SZ_QF  = (size_t)MR * DM * 4;
    const size_t SZ_QBF = (size_t)MR * DM * 2;
    const size_t SZ_PML = (size_t)48 * SN * NCH * 4;
    const size_t SZ_PO  = (size_t)48 * SN * NCH * HD * 2;   // bf16 partials

    char* ws = (char*)d_ws;
    float* qf    = (float*)ws; ws += al(SZ_QF);
    float* kfb   = (float*)ws; ws += al(SZ_QF);
    float* vfb   = (float*)ws; ws += al(SZ_QF);
    short* qbf   = (short*)ws; ws += al(SZ_QBF);
    short* xb    = (short*)ws; ws += al(SZ_QBF);
    short* attnb = (short*)ws; ws += al(SZ_QBF);
    float* pM    = (float*)ws; ws += al(SZ_PML);
    float* pL    = (float*)ws; ws += al(SZ_PML);
    short* pO    = (short*)ws; ws += al(SZ_PO);

    xcast<<<dim3(768), 256, 0, stream>>>(x, xb);
    gemm_bias<<<dim3(48, 4, 3), 256, 0, stream>>>(xb, Wq, Wk, Wv, bq, bk, bv, qf, kfb, vfb);
    norm_rope<<<dim3(1024), 256, 0, stream>>>(qf, kfb, qbf, gq, gk, freqs);
    attn_fa<<<dim3(432), 512, 0, stream>>>(qbf, kfb, vfb, kcache, vcache, pO, pM, pL);
    combine<<<dim3(12288), 128, 0, stream>>>(pO, pM, pL, attnb);
    gemm_bias<<<dim3(48, 4, 1), 256, 0, stream>>>(attnb, Wo, Wo, Wo, bo, bo, bo, out, out, out);
}

// Round 13
// 272.316 us; speedup vs baseline: 1.0950x; 1.0950x over previous
//
#include <hip/hip_runtime.h>
#include <hip/hip_bf16.h>

#define NH 24
#define HD 128
#define DM 3072
#define NB 2
#define SN 256
#define MR 512            // NB*SN rows
#define SCACHE 8192
#define NCH 9             // 6 chunks of 15 tiles + 3 of 14 tiles (132 tiles of 64 keys)

typedef float f32x4 __attribute__((ext_vector_type(4)));
typedef float f32x2 __attribute__((ext_vector_type(2)));
typedef short s16x8 __attribute__((ext_vector_type(8)));
typedef short s16x4 __attribute__((ext_vector_type(4)));
typedef unsigned u32x4 __attribute__((ext_vector_type(4)));

__device__ __forceinline__ short bfc(float f) {
    __hip_bfloat16 h = __float2bfloat16(f);
    return __builtin_bit_cast(short, h);
}

// ---------------- x -> bf16 (one-time cast) ----------------
__global__ __launch_bounds__(256) void xcast(const float* __restrict__ src, short* __restrict__ dst)
{
    const int i = (blockIdx.x * 256 + threadIdx.x) * 8;
    f32x4 a = *(const f32x4*)(src + i);
    f32x4 b = *(const f32x4*)(src + i + 4);
    s16x8 o;
    #pragma unroll
    for (int j = 0; j < 4; ++j) { o[j] = bfc(a[j]); o[4 + j] = bfc(b[j]); }
    *(s16x8*)(dst + i) = o;
}

// ---------------- GEMM: O[m,n] = sum_k A[m,k]*W[n,k] + bias[n] (bf16 A) ----------------
__global__ __launch_bounds__(256, 3) void gemm_bias(
    const short* __restrict__ A,
    const float* __restrict__ W0, const float* __restrict__ W1, const float* __restrict__ W2,
    const float* __restrict__ b0, const float* __restrict__ b1, const float* __restrict__ b2,
    float* __restrict__ O0, float* __restrict__ O1, float* __restrict__ O2)
{
    const int z = blockIdx.z;
    const float* W    = (z == 0) ? W0 : (z == 1) ? W1 : W2;
    const float* bias = (z == 0) ? b0 : (z == 1) ? b1 : b2;
    float* O          = (z == 0) ? O0 : (z == 1) ? O1 : O2;

    const int n0 = blockIdx.x * 64;
    const int m0 = blockIdx.y * 128;
    const int t = threadIdx.x;
    const int lane = t & 63;
    const int wave = t >> 6;
    const int l15 = lane & 15, l4 = lane >> 4;
    const int wm = wave * 32;

    __shared__ short As[128][72];
    __shared__ short Bs[64][72];

    f32x4 acc[2][4] = {};
    s16x8 areg[4];
    f32x4 breg[4];

    #pragma unroll
    for (int i = 0; i < 4; ++i) {
        int lin = i * 256 + t;
        areg[i] = *(const s16x8*)(A + (size_t)(m0 + (lin >> 3)) * DM + (lin & 7) * 8);
    }
    #pragma unroll
    for (int i = 0; i < 4; ++i) {
        int lin = i * 256 + t;
        breg[i] = *(const f32x4*)(W + (size_t)(n0 + (lin >> 4)) * DM + (lin & 15) * 4);
    }

    for (int ks = 0; ks < DM / 64; ++ks) {
        #pragma unroll
        for (int i = 0; i < 4; ++i) {
            int lin = i * 256 + t;
            *(s16x8*)&As[lin >> 3][(lin & 7) * 8] = areg[i];
        }
        #pragma unroll
        for (int i = 0; i < 4; ++i) {
            int lin = i * 256 + t;
            s16x4 w4;
            #pragma unroll
            for (int j = 0; j < 4; ++j) w4[j] = bfc(breg[i][j]);
            *(s16x4*)&Bs[lin >> 4][(lin & 15) * 4] = w4;
        }
        __syncthreads();
        if (ks + 1 < DM / 64) {
            int k0 = (ks + 1) * 64;
            #pragma unroll
            for (int i = 0; i < 4; ++i) {
                int lin = i * 256 + t;
                areg[i] = *(const s16x8*)(A + (size_t)(m0 + (lin >> 3)) * DM + k0 + (lin & 7) * 8);
            }
            #pragma unroll
            for (int i = 0; i < 4; ++i) {
                int lin = i * 256 + t;
                breg[i] = *(const f32x4*)(W + (size_t)(n0 + (lin >> 4)) * DM + k0 + (lin & 15) * 4);
            }
        }
        #pragma unroll
        for (int kt = 0; kt < 2; ++kt) {
            s16x8 af[2], bfr[4];
            #pragma unroll
            for (int i = 0; i < 2; ++i)
                af[i]  = *(const s16x8*)&As[wm + i * 16 + l15][kt * 32 + l4 * 8];
            #pragma unroll
            for (int i = 0; i < 4; ++i)
                bfr[i] = *(const s16x8*)&Bs[i * 16 + l15][kt * 32 + l4 * 8];
            #pragma unroll
            for (int mi = 0; mi < 2; ++mi)
                #pragma unroll
                for (int ni = 0; ni < 4; ++ni)
                    acc[mi][ni] = __builtin_amdgcn_mfma_f32_16x16x32_bf16(
                        af[mi], bfr[ni], acc[mi][ni], 0, 0, 0);
        }
        __syncthreads();
    }

    #pragma unroll
    for (int ni = 0; ni < 4; ++ni) {
        int col = n0 + ni * 16 + l15;
        float bv = bias[col];
        #pragma unroll
        for (int mi = 0; mi < 2; ++mi) {
            int row = m0 + wm + mi * 16 + l4 * 4;
            #pragma unroll
            for (int r = 0; r < 4; ++r)
                O[(size_t)(row + r) * DM + col] = acc[mi][ni][r] + bv;
        }
    }
}

// ---------------- RMSNorm + RoPE; Q pre-scaled by 1/sqrt(128)*log2e -> bf16 ----------------
__global__ __launch_bounds__(256) void norm_rope(
    float* __restrict__ qf, float* __restrict__ kf, short* __restrict__ qbf,
    const float* __restrict__ gq, const float* __restrict__ gk,
    const float* __restrict__ freqs)
{
    const int buf = blockIdx.x >> 9;
    const int row = blockIdx.x & 511;
    const int t = threadIdx.x;
    float* src = buf ? kf : qf;
    const float* g = buf ? gk : gq;

    f32x2 v[6];
    float ss = 0.f;
    #pragma unroll
    for (int i = 0; i < 6; ++i) {
        int p = t + 256 * i;
        v[i] = *(const f32x2*)(src + (size_t)row * DM + 2 * p);
        ss += v[i][0] * v[i][0] + v[i][1] * v[i][1];
    }
    #pragma unroll
    for (int m = 1; m < 64; m <<= 1) ss += __shfl_xor(ss, m);
    __shared__ float red[4];
    if ((t & 63) == 0) red[t >> 6] = ss;
    __syncthreads();
    ss = red[0] + red[1] + red[2] + red[3];
    const float scale = rsqrtf(ss * (1.0f / DM) + 1e-6f);
    const float QS = 0.08838834764831845f * 1.4426950408889634f; // 1/sqrt(128)*log2e

    const int spos = row & 255;
    #pragma unroll
    for (int i = 0; i < 6; ++i) {
        int p = t + 256 * i;
        int d2 = p & 63;
        float fr = freqs[spos * 64 + d2];
        float snv, cs;
        __sincosf(fr, &snv, &cs);
        f32x2 gg = *(const f32x2*)(g + 2 * p);
        float re = v[i][0] * scale * gg[0];
        float im = v[i][1] * scale * gg[1];
        float re2 = re * cs - im * snv;
        float im2 = re * snv + im * cs;
        if (buf == 0) {
            re2 *= QS; im2 *= QS;
            unsigned pack = (unsigned)(unsigned short)bfc(re2)
                          | ((unsigned)(unsigned short)bfc(im2) << 16);
            *(unsigned*)(qbf + (size_t)row * DM + 2 * p) = pack;
        } else {
            f32x2 o; o[0] = re2; o[1] = im2;
            *(f32x2*)(src + (size_t)row * DM + 2 * p) = o;
        }
    }
}

// ---------------- Flash attention: swapped QK^T, in-reg P, dbuf LDS, lazy softmax,
// ones-row-L (denominator via MFMA), max3 tree, per-tile base hoist ----------------
__global__ __launch_bounds__(512, 2) void attn_fa(
    const short* __restrict__ qbf,
    const float* __restrict__ kf, const float* __restrict__ vf,
    const float* __restrict__ kcache, const float* __restrict__ vcache,
    short* __restrict__ partO, float* __restrict__ partM, float* __restrict__ partL)
{
    const int bid = blockIdx.x;               // 0..431
    const int linear = (bid & 7) * 54 + (bid >> 3);
    const int c  = linear / 48;
    const int bh = linear % 48;
    const int b = bh / NH, h = bh % NH;
    const int t = threadIdx.x, lane = t & 63, wave = t >> 6;
    const int l15 = lane & 15, l4 = lane >> 4;
    const int hoff = h * HD;

    __shared__ short KsA[2][64 * 128];   // [k][d] 256B rows, chunk-swizzled
    __shared__ short VtA[2][128 * 64];   // [d][k] 128B rows, chunk-swizzled

    // Q B-fragments
    s16x8 qb[2][4];
    #pragma unroll
    for (int nj = 0; nj < 2; ++nj) {
        int qrow = b * SN + wave * 32 + nj * 16 + l15;
        #pragma unroll
        for (int kt = 0; kt < 4; ++kt)
            qb[nj][kt] = *(const s16x8*)(qbf + (size_t)qrow * DM + hoff + kt * 32 + l4 * 8);
    }

    f32x4 acc[2][8] = {};
    f32x4 accL[2] = {};                  // ones-row PV -> per-q softmax denominator
    float mrun[2] = {-INFINITY, -INFINITY};

    s16x8 ones1;
    #pragma unroll
    for (int j = 0; j < 8; ++j) ones1[j] = (short)0x3F80;   // bf16 1.0

    const int ts = (c < 6) ? c * 15 : 90 + (c - 6) * 14;
    const int NT = (c < 6) ? 15 : 14;

    const float* kcB = kcache + (size_t)b * SCACHE * DM + hoff;
    const float* knB = kf     + (size_t)b * SN * DM + hoff;
    const float* vcB = vcache + (size_t)b * SCACHE * DM + hoff;
    const float* vnB = vf     + (size_t)b * SN * DM + hoff;

    const int vrow = t & 63, vw = t >> 6;
    f32x4 kreg[4], vreg[4];

    // prologue: tile 0 loads (base hoisted, wave-uniform select)
    {
        const int kr = ts * 64;
        const float* kb; const float* vb;
        if (kr < SCACHE) { kb = kcB + (size_t)kr * DM; vb = vcB + (size_t)kr * DM; }
        else             { kb = knB + (size_t)(kr - SCACHE) * DM; vb = vnB + (size_t)(kr - SCACHE) * DM; }
        #pragma unroll
        for (int i = 0; i < 4; ++i) {
            int lin = i * 512 + t;
            kreg[i] = *(const f32x4*)(kb + (size_t)(lin >> 5) * DM + (lin & 31) * 4);
        }
        #pragma unroll
        for (int j = 0; j < 4; ++j)
            vreg[j] = *(const f32x4*)(vb + (size_t)vrow * DM + vw * 16 + j * 4);
    }

    const bool ghi = (l4 & 2) != 0;
    const bool gin = (l4 == 0) || (l4 == 3);

    for (int nt = 0; nt < NT; ++nt) {
        char* KsB = (char*)KsA[nt & 1];
        char* VtB = (char*)VtA[nt & 1];

        // ---- stage regs -> LDS buf[nt&1] (chunk-swizzled) ----
        #pragma unroll
        for (int i = 0; i < 4; ++i) {
            int lin = i * 512 + t;
            int row = lin >> 5, col4 = lin & 31;
            s16x4 k4;
            #pragma unroll
            for (int j = 0; j < 4; ++j) k4[j] = bfc(kreg[i][j]);
            *(s16x4*)(KsB + (row << 8) + ((((col4 >> 1) ^ row) & 15) << 4) + ((col4 & 1) << 3)) = k4;
        }
        #pragma unroll
        for (int j = 0; j < 4; ++j) {
            #pragma unroll
            for (int jj = 0; jj < 4; ++jj) {
                int d = vw * 16 + j * 4 + jj;
                *(short*)(VtB + (d << 7) + ((((vrow >> 3) ^ (d & 7))) << 4) + ((vrow & 7) << 1)) = bfc(vreg[j][jj]);
            }
        }
        __syncthreads();   // single barrier per tile (double-buffered)

        // ---- issue next-tile loads (base hoisted; fly across all compute) ----
        if (nt + 1 < NT) {
            const int kr1 = (ts + nt + 1) * 64;
            const float* kb; const float* vb;
            if (kr1 < SCACHE) { kb = kcB + (size_t)kr1 * DM; vb = vcB + (size_t)kr1 * DM; }
            else              { kb = knB + (size_t)(kr1 - SCACHE) * DM; vb = vnB + (size_t)(kr1 - SCACHE) * DM; }
            #pragma unroll
            for (int i = 0; i < 4; ++i) {
                int lin = i * 512 + t;
                kreg[i] = *(const f32x4*)(kb + (size_t)(lin >> 5) * DM + (lin & 31) * 4);
            }
            #pragma unroll
            for (int j = 0; j < 4; ++j)
                vreg[j] = *(const f32x4*)(vb + (size_t)vrow * DM + vw * 16 + j * 4);
        }

        // ---- S^T = K * Q^T ----
        f32x4 st[4][2] = {};
        #pragma unroll
        for (int kt = 0; kt < 4; ++kt)
            #pragma unroll
            for (int mi = 0; mi < 4; ++mi) {
                int row = mi * 16 + l15;
                s16x8 kfr = *(const s16x8*)(KsB + (row << 8) + (((kt * 4 + l4) ^ l15) << 4));
                st[mi][0] = __builtin_amdgcn_mfma_f32_16x16x32_bf16(kfr, qb[0][kt], st[mi][0], 0, 0, 0);
                st[mi][1] = __builtin_amdgcn_mfma_f32_16x16x32_bf16(kfr, qb[1][kt], st[mi][1], 0, 0, 0);
            }

        // ---- online softmax: max3-grouped in-lane tree, lazy cross-lane ----
        float a0 = fmaxf(fmaxf(st[0][0][0], st[0][0][1]), st[0][0][2]);
        float a1 = fmaxf(fmaxf(st[0][0][3], st[1][0][0]), st[1][0][1]);
        float a2 = fmaxf(fmaxf(st[1][0][2], st[1][0][3]), st[2][0][0]);
        float a3 = fmaxf(fmaxf(st[2][0][1], st[2][0][2]), st[2][0][3]);
        float a4 = fmaxf(fmaxf(st[3][0][0], st[3][0][1]), st[3][0][2]);
        float lx0 = fmaxf(fmaxf(fmaxf(a0, a1), a2), fmaxf(fmaxf(a3, a4), st[3][0][3]));
        float b0_ = fmaxf(fmaxf(st[0][1][0], st[0][1][1]), st[0][1][2]);
        float b1_ = fmaxf(fmaxf(st[0][1][3], st[1][1][0]), st[1][1][1]);
        float b2_ = fmaxf(fmaxf(st[1][1][2], st[1][1][3]), st[2][1][0]);
        float b3_ = fmaxf(fmaxf(st[2][1][1], st[2][1][2]), st[2][1][3]);
        float b4_ = fmaxf(fmaxf(st[3][1][0], st[3][1][1]), st[3][1][2]);
        float lx1 = fmaxf(fmaxf(fmaxf(b0_, b1_), b2_), fmaxf(fmaxf(b3_, b4_), st[3][1][3]));

        if (!__all((lx0 <= mrun[0] + 8.0f) && (lx1 <= mrun[1] + 8.0f))) {
            float lm0 = fmaxf(lx0, __shfl_xor(lx0, 16)); lm0 = fmaxf(lm0, __shfl_xor(lm0, 32));
            float lm1 = fmaxf(lx1, __shfl_xor(lx1, 16)); lm1 = fmaxf(lm1, __shfl_xor(lm1, 32));
            float mn0 = fmaxf(mrun[0], lm0), mn1 = fmaxf(mrun[1], lm1);
            float c0 = exp2f(mrun[0] - mn0), c1 = exp2f(mrun[1] - mn1);
            mrun[0] = mn0; mrun[1] = mn1;
            accL[0] *= c0; accL[1] *= c1;
            #pragma unroll
            for (int df = 0; df < 8; ++df) { acc[0][df] *= c0; acc[1][df] *= c1; }
        }

        #pragma unroll
        for (int mi = 0; mi < 4; ++mi)
            #pragma unroll
            for (int r = 0; r < 4; ++r) {
                st[mi][0][r] = exp2f(st[mi][0][r] - mrun[0]);
                st[mi][1][r] = exp2f(st[mi][1][r] - mrun[1]);
            }

        // ---- pack P to bf16 pairs ----
        unsigned up[2][4][2];
        #pragma unroll
        for (int nj = 0; nj < 2; ++nj)
            #pragma unroll
            for (int mi = 0; mi < 4; ++mi)
                #pragma unroll
                for (int i = 0; i < 2; ++i)
                    up[nj][mi][i] = (unsigned)(unsigned short)bfc(st[mi][nj][2 * i])
                                  | ((unsigned)(unsigned short)bfc(st[mi][nj][2 * i + 1]) << 16);

        // ---- cross-group exchange -> PV B-frags ----
        s16x8 bp[2][2];
        #pragma unroll
        for (int nj = 0; nj < 2; ++nj)
            #pragma unroll
            for (int kt2 = 0; kt2 < 2; ++kt2) {
                unsigned own0 = ghi ? up[nj][kt2 * 2 + 1][0] : up[nj][kt2 * 2 + 0][0];
                unsigned own1 = ghi ? up[nj][kt2 * 2 + 1][1] : up[nj][kt2 * 2 + 0][1];
                unsigned alt0 = ghi ? up[nj][kt2 * 2 + 0][0] : up[nj][kt2 * 2 + 1][0];
                unsigned alt1 = ghi ? up[nj][kt2 * 2 + 0][1] : up[nj][kt2 * 2 + 1][1];
                unsigned o16_0 = __shfl_xor(own0, 16), o16_1 = __shfl_xor(own1, 16);
                unsigned o32_0 = __shfl_xor(alt0, 32), o32_1 = __shfl_xor(alt1, 32);
                unsigned o48_0 = __shfl_xor(alt0, 48), o48_1 = __shfl_xor(alt1, 48);
                u32x4 uu;
                uu[0] = gin ? (ghi ? o16_0 : own0) : (ghi ? o32_0 : o48_0);
                uu[1] = gin ? (ghi ? o16_1 : own1) : (ghi ? o32_1 : o48_1);
                uu[2] = gin ? (ghi ? own0 : o16_0) : (ghi ? o48_0 : o32_0);
                uu[3] = gin ? (ghi ? own1 : o16_1) : (ghi ? o48_1 : o32_1);
                bp[nj][kt2] = __builtin_bit_cast(s16x8, uu);
            }

        // ---- PV (+ ones-row for L) ----
        #pragma unroll
        for (int kt2 = 0; kt2 < 2; ++kt2) {
            #pragma unroll
            for (int df = 0; df < 8; ++df) {
                int row = df * 16 + l15;
                s16x8 vfr = *(const s16x8*)(VtB + (row << 7) + (((kt2 * 4 + l4) ^ (row & 7)) << 4));
                acc[0][df] = __builtin_amdgcn_mfma_f32_16x16x32_bf16(vfr, bp[0][kt2], acc[0][df], 0, 0, 0);
                acc[1][df] = __builtin_amdgcn_mfma_f32_16x16x32_bf16(vfr, bp[1][kt2], acc[1][df], 0, 0, 0);
            }
            accL[0] = __builtin_amdgcn_mfma_f32_16x16x32_bf16(ones1, bp[0][kt2], accL[0], 0, 0, 0);
            accL[1] = __builtin_amdgcn_mfma_f32_16x16x32_bf16(ones1, bp[1][kt2], accL[1], 0, 0, 0);
        }
    }

    // ---- write partials (bf16 O; L directly from accL, no cross-lane reduce) ----
    #pragma unroll
    for (int nj = 0; nj < 2; ++nj) {
        size_t rowid = (size_t)bh * SN + wave * 32 + nj * 16 + l15;
        short* po = partO + (rowid * NCH + c) * HD + l4 * 4;
        #pragma unroll
        for (int df = 0; df < 8; ++df) {
            s16x4 ob;
            #pragma unroll
            for (int r = 0; r < 4; ++r) ob[r] = bfc(acc[nj][df][r]);
            *(s16x4*)(po + df * 16) = ob;
        }
        if (l4 == 0) {
            partM[rowid * NCH + c] = mrun[nj];
            partL[rowid * NCH + c] = accL[nj][0];
        }
    }
}

// ---------------- combine split-K partials (bf16 partO -> bf16 attn) ----------------
__global__ __launch_bounds__(128) void combine(
    const short* __restrict__ partO, const float* __restrict__ partM,
    const float* __restrict__ partL, short* __restrict__ attnb)
{
    const int rowid = blockIdx.x;        // bh*256 + q
    const int bh = rowid >> 8, q = rowid & 255;
    const int b = bh / NH, h = bh % NH;
    const int d = threadIdx.x;

    float m[NCH];
    float M = -INFINITY;
    #pragma unroll
    for (int c = 0; c < NCH; ++c) { m[c] = partM[(size_t)rowid * NCH + c]; M = fmaxf(M, m[c]); }
    float L = 0.f, o = 0.f;
    #pragma unroll
    for (int c = 0; c < NCH; ++c) {
        float w = exp2f(m[c] - M);
        L += partL[(size_t)rowid * NCH + c] * w;
        unsigned ub = (unsigned)(unsigned short)partO[((size_t)rowid * NCH + c) * HD + d];
        float ov = __builtin_bit_cast(float, ub << 16);
        o += ov * w;
    }
    attnb[(size_t)(b * SN + q) * DM + h * HD + d] = bfc(o / L);
}

extern "C" void kernel_launch(void* const* d_in, const int* in_sizes, int n_in,
                              void* d_out, int out_size, void* d_ws, size_t ws_size,
                              hipStream_t stream) {
    const float* x      = (const float*)d_in[0];
    const float* freqs  = (const float*)d_in[1];
    const float* kcache = (const float*)d_in[2];
    const float* vcache = (const float*)d_in[3];
    const float* Wq = (const float*)d_in[4];
    const float* bq = (const float*)d_in[5];
    const float* Wk = (const float*)d_in[6];
    const float* bk = (const float*)d_in[7];
    const float* Wv = (const float*)d_in[8];
    const float* bv = (const float*)d_in[9];
    const float* Wo = (const float*)d_in[10];
    const float* bo = (const float*)d_in[11];
    const float* gq = (const float*)d_in[12];
    const float* gk = (const float*)d_in[13];
    float* out = (float*)d_out;

    auto al = [](size_t v) { return (v + 255) & ~(size_t)255; };
    const size_t SZ_QF  = (size_t)MR * DM * 4;
    const size_t SZ_QBF = (size_t)MR * DM * 2;
    const size_t SZ_PML = (size_t)48 * SN * NCH * 4;
    const size_t SZ_PO  = (size_t)48 * SN * NCH * HD * 2;   // bf16 partials

    char* ws = (char*)d_ws;
    float* qf    = (float*)ws; ws += al(SZ_QF);
    float* kfb   = (float*)ws; ws += al(SZ_QF);
    float* vfb   = (float*)ws; ws += al(SZ_QF);
    short* qbf   = (short*)ws; ws += al(SZ_QBF);
    short* xb    = (short*)ws; ws += al(SZ_QBF);
    short* attnb = (short*)ws; ws += al(SZ_QBF);
    float* pM    = (float*)ws; ws += al(SZ_PML);
    float* pL    = (float*)ws; ws += al(SZ_PML);
    short* pO    = (short*)ws; ws += al(SZ_PO);

    xcast<<<dim3(768), 256, 0, stream>>>(x, xb);
    gemm_bias<<<dim3(48, 4, 3), 256, 0, stream>>>(xb, Wq, Wk, Wv, bq, bk, bv, qf, kfb, vfb);
    norm_rope<<<dim3(1024), 256, 0, stream>>>(qf, kfb, qbf, gq, gk, freqs);
    attn_fa<<<dim3(432), 512, 0, stream>>>(qbf, kfb, vfb, kcache, vcache, pO, pM, pL);
    combine<<<dim3(12288), 128, 0, stream>>>(pO, pM, pL, attnb);
    gemm_bias<<<dim3(48, 4, 1), 256, 0, stream>>>(attnb, Wo, Wo, Wo, bo, bo, bo, out, out, out);
}

// Round 14
// 269.235 us; speedup vs baseline: 1.1075x; 1.0114x over previous
//
#include <hip/hip_runtime.h>
#include <hip/hip_bf16.h>

#define NH 24
#define HD 128
#define DM 3072
#define NB 2
#define SN 256
#define MR 512            // NB*SN rows
#define SCACHE 8192
#define NCH 9             // 6 chunks of 15 tiles + 3 of 14 tiles (132 tiles of 64 keys)

typedef float f32x4 __attribute__((ext_vector_type(4)));
typedef float f32x2 __attribute__((ext_vector_type(2)));
typedef short s16x8 __attribute__((ext_vector_type(8)));
typedef short s16x4 __attribute__((ext_vector_type(4)));
typedef unsigned u32x4 __attribute__((ext_vector_type(4)));

__device__ __forceinline__ short bfc(float f) {
    __hip_bfloat16 h = __float2bfloat16(f);
    return __builtin_bit_cast(short, h);
}

// round-half-up bf16 pair pack: high16(a+0x8000) -> low, high16(b+0x8000) -> high.
// 0.5-ulp max error (same as RNE); assumes finite inputs (weights/activations).
__device__ __forceinline__ unsigned bpack2(float a, float b) {
    unsigned ua = __builtin_bit_cast(unsigned, a) + 0x8000u;
    unsigned ub = __builtin_bit_cast(unsigned, b) + 0x8000u;
    return __builtin_amdgcn_perm(ub, ua, 0x07060302u);   // {ub.b3,ub.b2,ua.b3,ua.b2}
}

// ---------------- x -> bf16 (one-time cast) ----------------
__global__ __launch_bounds__(256) void xcast(const float* __restrict__ src, short* __restrict__ dst)
{
    const int i = (blockIdx.x * 256 + threadIdx.x) * 8;
    f32x4 a = *(const f32x4*)(src + i);
    f32x4 b = *(const f32x4*)(src + i + 4);
    s16x8 o;
    #pragma unroll
    for (int j = 0; j < 4; ++j) { o[j] = bfc(a[j]); o[4 + j] = bfc(b[j]); }
    *(s16x8*)(dst + i) = o;
}

// ---------------- GEMM: O[m,n] = sum_k A[m,k]*W[n,k] + bias[n] (bf16 A, fast W pack) ----------------
__global__ __launch_bounds__(256, 3) void gemm_bias(
    const short* __restrict__ A,
    const float* __restrict__ W0, const float* __restrict__ W1, const float* __restrict__ W2,
    const float* __restrict__ b0, const float* __restrict__ b1, const float* __restrict__ b2,
    float* __restrict__ O0, float* __restrict__ O1, float* __restrict__ O2)
{
    const int z = blockIdx.z;
    const float* W    = (z == 0) ? W0 : (z == 1) ? W1 : W2;
    const float* bias = (z == 0) ? b0 : (z == 1) ? b1 : b2;
    float* O          = (z == 0) ? O0 : (z == 1) ? O1 : O2;

    const int n0 = blockIdx.x * 64;
    const int m0 = blockIdx.y * 128;
    const int t = threadIdx.x;
    const int lane = t & 63;
    const int wave = t >> 6;
    const int l15 = lane & 15, l4 = lane >> 4;
    const int wm = wave * 32;

    __shared__ short As[128][72];
    __shared__ short Bs[64][72];

    f32x4 acc[2][4] = {};
    s16x8 areg[4];
    f32x4 breg[4];

    #pragma unroll
    for (int i = 0; i < 4; ++i) {
        int lin = i * 256 + t;
        areg[i] = *(const s16x8*)(A + (size_t)(m0 + (lin >> 3)) * DM + (lin & 7) * 8);
    }
    #pragma unroll
    for (int i = 0; i < 4; ++i) {
        int lin = i * 256 + t;
        breg[i] = *(const f32x4*)(W + (size_t)(n0 + (lin >> 4)) * DM + (lin & 15) * 4);
    }

    for (int ks = 0; ks < DM / 64; ++ks) {
        #pragma unroll
        for (int i = 0; i < 4; ++i) {
            int lin = i * 256 + t;
            *(s16x8*)&As[lin >> 3][(lin & 7) * 8] = areg[i];
        }
        #pragma unroll
        for (int i = 0; i < 4; ++i) {
            int lin = i * 256 + t;
            unsigned p01 = bpack2(breg[i][0], breg[i][1]);
            unsigned p23 = bpack2(breg[i][2], breg[i][3]);
            unsigned* dst = (unsigned*)&Bs[lin >> 4][(lin & 15) * 4];
            dst[0] = p01; dst[1] = p23;
        }
        __syncthreads();
        if (ks + 1 < DM / 64) {
            int k0 = (ks + 1) * 64;
            #pragma unroll
            for (int i = 0; i < 4; ++i) {
                int lin = i * 256 + t;
                areg[i] = *(const s16x8*)(A + (size_t)(m0 + (lin >> 3)) * DM + k0 + (lin & 7) * 8);
            }
            #pragma unroll
            for (int i = 0; i < 4; ++i) {
                int lin = i * 256 + t;
                breg[i] = *(const f32x4*)(W + (size_t)(n0 + (lin >> 4)) * DM + k0 + (lin & 15) * 4);
            }
        }
        #pragma unroll
        for (int kt = 0; kt < 2; ++kt) {
            s16x8 af[2], bfr[4];
            #pragma unroll
            for (int i = 0; i < 2; ++i)
                af[i]  = *(const s16x8*)&As[wm + i * 16 + l15][kt * 32 + l4 * 8];
            #pragma unroll
            for (int i = 0; i < 4; ++i)
                bfr[i] = *(const s16x8*)&Bs[i * 16 + l15][kt * 32 + l4 * 8];
            #pragma unroll
            for (int mi = 0; mi < 2; ++mi)
                #pragma unroll
                for (int ni = 0; ni < 4; ++ni)
                    acc[mi][ni] = __builtin_amdgcn_mfma_f32_16x16x32_bf16(
                        af[mi], bfr[ni], acc[mi][ni], 0, 0, 0);
        }
        __syncthreads();
    }

    #pragma unroll
    for (int ni = 0; ni < 4; ++ni) {
        int col = n0 + ni * 16 + l15;
        float bv = bias[col];
        #pragma unroll
        for (int mi = 0; mi < 2; ++mi) {
            int row = m0 + wm + mi * 16 + l4 * 4;
            #pragma unroll
            for (int r = 0; r < 4; ++r)
                O[(size_t)(row + r) * DM + col] = acc[mi][ni][r] + bv;
        }
    }
}

// ---------------- RMSNorm + RoPE; Q pre-scaled by 1/sqrt(128)*log2e -> bf16 ----------------
__global__ __launch_bounds__(256) void norm_rope(
    float* __restrict__ qf, float* __restrict__ kf, short* __restrict__ qbf,
    const float* __restrict__ gq, const float* __restrict__ gk,
    const float* __restrict__ freqs)
{
    const int buf = blockIdx.x >> 9;
    const int row = blockIdx.x & 511;
    const int t = threadIdx.x;
    float* src = buf ? kf : qf;
    const float* g = buf ? gk : gq;

    f32x2 v[6];
    float ss = 0.f;
    #pragma unroll
    for (int i = 0; i < 6; ++i) {
        int p = t + 256 * i;
        v[i] = *(const f32x2*)(src + (size_t)row * DM + 2 * p);
        ss += v[i][0] * v[i][0] + v[i][1] * v[i][1];
    }
    #pragma unroll
    for (int m = 1; m < 64; m <<= 1) ss += __shfl_xor(ss, m);
    __shared__ float red[4];
    if ((t & 63) == 0) red[t >> 6] = ss;
    __syncthreads();
    ss = red[0] + red[1] + red[2] + red[3];
    const float scale = rsqrtf(ss * (1.0f / DM) + 1e-6f);
    const float QS = 0.08838834764831845f * 1.4426950408889634f; // 1/sqrt(128)*log2e

    const int spos = row & 255;
    #pragma unroll
    for (int i = 0; i < 6; ++i) {
        int p = t + 256 * i;
        int d2 = p & 63;
        float fr = freqs[spos * 64 + d2];
        float snv, cs;
        __sincosf(fr, &snv, &cs);
        f32x2 gg = *(const f32x2*)(g + 2 * p);
        float re = v[i][0] * scale * gg[0];
        float im = v[i][1] * scale * gg[1];
        float re2 = re * cs - im * snv;
        float im2 = re * snv + im * cs;
        if (buf == 0) {
            re2 *= QS; im2 *= QS;
            unsigned pack = (unsigned)(unsigned short)bfc(re2)
                          | ((unsigned)(unsigned short)bfc(im2) << 16);
            *(unsigned*)(qbf + (size_t)row * DM + 2 * p) = pack;
        } else {
            f32x2 o; o[0] = re2; o[1] = im2;
            *(f32x2*)(src + (size_t)row * DM + 2 * p) = o;
        }
    }
}

// ---------------- Flash attention: swapped QK^T, in-reg P, dbuf LDS, lazy softmax,
// ones-row-L (denominator via MFMA), max3 tree, per-tile base hoist (R11/R13 frozen) ----------------
__global__ __launch_bounds__(512, 2) void attn_fa(
    const short* __restrict__ qbf,
    const float* __restrict__ kf, const float* __restrict__ vf,
    const float* __restrict__ kcache, const float* __restrict__ vcache,
    short* __restrict__ partO, float* __restrict__ partM, float* __restrict__ partL)
{
    const int bid = blockIdx.x;               // 0..431
    const int linear = (bid & 7) * 54 + (bid >> 3);
    const int c  = linear / 48;
    const int bh = linear % 48;
    const int b = bh / NH, h = bh % NH;
    const int t = threadIdx.x, lane = t & 63, wave = t >> 6;
    const int l15 = lane & 15, l4 = lane >> 4;
    const int hoff = h * HD;

    __shared__ short KsA[2][64 * 128];   // [k][d] 256B rows, chunk-swizzled
    __shared__ short VtA[2][128 * 64];   // [d][k] 128B rows, chunk-swizzled

    // Q B-fragments
    s16x8 qb[2][4];
    #pragma unroll
    for (int nj = 0; nj < 2; ++nj) {
        int qrow = b * SN + wave * 32 + nj * 16 + l15;
        #pragma unroll
        for (int kt = 0; kt < 4; ++kt)
            qb[nj][kt] = *(const s16x8*)(qbf + (size_t)qrow * DM + hoff + kt * 32 + l4 * 8);
    }

    f32x4 acc[2][8] = {};
    f32x4 accL[2] = {};                  // ones-row PV -> per-q softmax denominator
    float mrun[2] = {-INFINITY, -INFINITY};

    s16x8 ones1;
    #pragma unroll
    for (int j = 0; j < 8; ++j) ones1[j] = (short)0x3F80;   // bf16 1.0

    const int ts = (c < 6) ? c * 15 : 90 + (c - 6) * 14;
    const int NT = (c < 6) ? 15 : 14;

    const float* kcB = kcache + (size_t)b * SCACHE * DM + hoff;
    const float* knB = kf     + (size_t)b * SN * DM + hoff;
    const float* vcB = vcache + (size_t)b * SCACHE * DM + hoff;
    const float* vnB = vf     + (size_t)b * SN * DM + hoff;

    const int vrow = t & 63, vw = t >> 6;
    f32x4 kreg[4], vreg[4];

    // prologue: tile 0 loads (base hoisted, wave-uniform select)
    {
        const int kr = ts * 64;
        const float* kb; const float* vb;
        if (kr < SCACHE) { kb = kcB + (size_t)kr * DM; vb = vcB + (size_t)kr * DM; }
        else             { kb = knB + (size_t)(kr - SCACHE) * DM; vb = vnB + (size_t)(kr - SCACHE) * DM; }
        #pragma unroll
        for (int i = 0; i < 4; ++i) {
            int lin = i * 512 + t;
            kreg[i] = *(const f32x4*)(kb + (size_t)(lin >> 5) * DM + (lin & 31) * 4);
        }
        #pragma unroll
        for (int j = 0; j < 4; ++j)
            vreg[j] = *(const f32x4*)(vb + (size_t)vrow * DM + vw * 16 + j * 4);
    }

    const bool ghi = (l4 & 2) != 0;
    const bool gin = (l4 == 0) || (l4 == 3);

    for (int nt = 0; nt < NT; ++nt) {
        char* KsB = (char*)KsA[nt & 1];
        char* VtB = (char*)VtA[nt & 1];

        // ---- stage regs -> LDS buf[nt&1] (chunk-swizzled) ----
        #pragma unroll
        for (int i = 0; i < 4; ++i) {
            int lin = i * 512 + t;
            int row = lin >> 5, col4 = lin & 31;
            s16x4 k4;
            #pragma unroll
            for (int j = 0; j < 4; ++j) k4[j] = bfc(kreg[i][j]);
            *(s16x4*)(KsB + (row << 8) + ((((col4 >> 1) ^ row) & 15) << 4) + ((col4 & 1) << 3)) = k4;
        }
        #pragma unroll
        for (int j = 0; j < 4; ++j) {
            #pragma unroll
            for (int jj = 0; jj < 4; ++jj) {
                int d = vw * 16 + j * 4 + jj;
                *(short*)(VtB + (d << 7) + ((((vrow >> 3) ^ (d & 7))) << 4) + ((vrow & 7) << 1)) = bfc(vreg[j][jj]);
            }
        }
        __syncthreads();   // single barrier per tile (double-buffered)

        // ---- issue next-tile loads (base hoisted; fly across all compute) ----
        if (nt + 1 < NT) {
            const int kr1 = (ts + nt + 1) * 64;
            const float* kb; const float* vb;
            if (kr1 < SCACHE) { kb = kcB + (size_t)kr1 * DM; vb = vcB + (size_t)kr1 * DM; }
            else              { kb = knB + (size_t)(kr1 - SCACHE) * DM; vb = vnB + (size_t)(kr1 - SCACHE) * DM; }
            #pragma unroll
            for (int i = 0; i < 4; ++i) {
                int lin = i * 512 + t;
                kreg[i] = *(const f32x4*)(kb + (size_t)(lin >> 5) * DM + (lin & 31) * 4);
            }
            #pragma unroll
            for (int j = 0; j < 4; ++j)
                vreg[j] = *(const f32x4*)(vb + (size_t)vrow * DM + vw * 16 + j * 4);
        }

        // ---- S^T = K * Q^T ----
        f32x4 st[4][2] = {};
        #pragma unroll
        for (int kt = 0; kt < 4; ++kt)
            #pragma unroll
            for (int mi = 0; mi < 4; ++mi) {
                int row = mi * 16 + l15;
                s16x8 kfr = *(const s16x8*)(KsB + (row << 8) + (((kt * 4 + l4) ^ l15) << 4));
                st[mi][0] = __builtin_amdgcn_mfma_f32_16x16x32_bf16(kfr, qb[0][kt], st[mi][0], 0, 0, 0);
                st[mi][1] = __builtin_amdgcn_mfma_f32_16x16x32_bf16(kfr, qb[1][kt], st[mi][1], 0, 0, 0);
            }

        // ---- online softmax: max3-grouped in-lane tree, lazy cross-lane ----
        float a0 = fmaxf(fmaxf(st[0][0][0], st[0][0][1]), st[0][0][2]);
        float a1 = fmaxf(fmaxf(st[0][0][3], st[1][0][0]), st[1][0][1]);
        float a2 = fmaxf(fmaxf(st[1][0][2], st[1][0][3]), st[2][0][0]);
        float a3 = fmaxf(fmaxf(st[2][0][1], st[2][0][2]), st[2][0][3]);
        float a4 = fmaxf(fmaxf(st[3][0][0], st[3][0][1]), st[3][0][2]);
        float lx0 = fmaxf(fmaxf(fmaxf(a0, a1), a2), fmaxf(fmaxf(a3, a4), st[3][0][3]));
        float b0_ = fmaxf(fmaxf(st[0][1][0], st[0][1][1]), st[0][1][2]);
        float b1_ = fmaxf(fmaxf(st[0][1][3], st[1][1][0]), st[1][1][1]);
        float b2_ = fmaxf(fmaxf(st[1][1][2], st[1][1][3]), st[2][1][0]);
        float b3_ = fmaxf(fmaxf(st[2][1][1], st[2][1][2]), st[2][1][3]);
        float b4_ = fmaxf(fmaxf(st[3][1][0], st[3][1][1]), st[3][1][2]);
        float lx1 = fmaxf(fmaxf(fmaxf(b0_, b1_), b2_), fmaxf(fmaxf(b3_, b4_), st[3][1][3]));

        if (!__all((lx0 <= mrun[0] + 8.0f) && (lx1 <= mrun[1] + 8.0f))) {
            float lm0 = fmaxf(lx0, __shfl_xor(lx0, 16)); lm0 = fmaxf(lm0, __shfl_xor(lm0, 32));
            float lm1 = fmaxf(lx1, __shfl_xor(lx1, 16)); lm1 = fmaxf(lm1, __shfl_xor(lm1, 32));
            float mn0 = fmaxf(mrun[0], lm0), mn1 = fmaxf(mrun[1], lm1);
            float c0 = exp2f(mrun[0] - mn0), c1 = exp2f(mrun[1] - mn1);
            mrun[0] = mn0; mrun[1] = mn1;
            accL[0] *= c0; accL[1] *= c1;
            #pragma unroll
            for (int df = 0; df < 8; ++df) { acc[0][df] *= c0; acc[1][df] *= c1; }
        }

        #pragma unroll
        for (int mi = 0; mi < 4; ++mi)
            #pragma unroll
            for (int r = 0; r < 4; ++r) {
                st[mi][0][r] = exp2f(st[mi][0][r] - mrun[0]);
                st[mi][1][r] = exp2f(st[mi][1][r] - mrun[1]);
            }

        // ---- pack P to bf16 pairs ----
        unsigned up[2][4][2];
        #pragma unroll
        for (int nj = 0; nj < 2; ++nj)
            #pragma unroll
            for (int mi = 0; mi < 4; ++mi)
                #pragma unroll
                for (int i = 0; i < 2; ++i)
                    up[nj][mi][i] = (unsigned)(unsigned short)bfc(st[mi][nj][2 * i])
                                  | ((unsigned)(unsigned short)bfc(st[mi][nj][2 * i + 1]) << 16);

        // ---- cross-group exchange -> PV B-frags ----
        s16x8 bp[2][2];
        #pragma unroll
        for (int nj = 0; nj < 2; ++nj)
            #pragma unroll
            for (int kt2 = 0; kt2 < 2; ++kt2) {
                unsigned own0 = ghi ? up[nj][kt2 * 2 + 1][0] : up[nj][kt2 * 2 + 0][0];
                unsigned own1 = ghi ? up[nj][kt2 * 2 + 1][1] : up[nj][kt2 * 2 + 0][1];
                unsigned alt0 = ghi ? up[nj][kt2 * 2 + 0][0] : up[nj][kt2 * 2 + 1][0];
                unsigned alt1 = ghi ? up[nj][kt2 * 2 + 0][1] : up[nj][kt2 * 2 + 1][1];
                unsigned o16_0 = __shfl_xor(own0, 16), o16_1 = __shfl_xor(own1, 16);
                unsigned o32_0 = __shfl_xor(alt0, 32), o32_1 = __shfl_xor(alt1, 32);
                unsigned o48_0 = __shfl_xor(alt0, 48), o48_1 = __shfl_xor(alt1, 48);
                u32x4 uu;
                uu[0] = gin ? (ghi ? o16_0 : own0) : (ghi ? o32_0 : o48_0);
                uu[1] = gin ? (ghi ? o16_1 : own1) : (ghi ? o32_1 : o48_1);
                uu[2] = gin ? (ghi ? own0 : o16_0) : (ghi ? o48_0 : o32_0);
                uu[3] = gin ? (ghi ? own1 : o16_1) : (ghi ? o48_1 : o32_1);
                bp[nj][kt2] = __builtin_bit_cast(s16x8, uu);
            }

        // ---- PV (+ ones-row for L) ----
        #pragma unroll
        for (int kt2 = 0; kt2 < 2; ++kt2) {
            #pragma unroll
            for (int df = 0; df < 8; ++df) {
                int row = df * 16 + l15;
                s16x8 vfr = *(const s16x8*)(VtB + (row << 7) + (((kt2 * 4 + l4) ^ (row & 7)) << 4));
                acc[0][df] = __builtin_amdgcn_mfma_f32_16x16x32_bf16(vfr, bp[0][kt2], acc[0][df], 0, 0, 0);
                acc[1][df] = __builtin_amdgcn_mfma_f32_16x16x32_bf16(vfr, bp[1][kt2], acc[1][df], 0, 0, 0);
            }
            accL[0] = __builtin_amdgcn_mfma_f32_16x16x32_bf16(ones1, bp[0][kt2], accL[0], 0, 0, 0);
            accL[1] = __builtin_amdgcn_mfma_f32_16x16x32_bf16(ones1, bp[1][kt2], accL[1], 0, 0, 0);
        }
    }

    // ---- write partials (bf16 O; L directly from accL, no cross-lane reduce) ----
    #pragma unroll
    for (int nj = 0; nj < 2; ++nj) {
        size_t rowid = (size_t)bh * SN + wave * 32 + nj * 16 + l15;
        short* po = partO + (rowid * NCH + c) * HD + l4 * 4;
        #pragma unroll
        for (int df = 0; df < 8; ++df) {
            s16x4 ob;
            #pragma unroll
            for (int r = 0; r < 4; ++r) ob[r] = bfc(acc[nj][df][r]);
            *(s16x4*)(po + df * 16) = ob;
        }
        if (l4 == 0) {
            partM[rowid * NCH + c] = mrun[nj];
            partL[rowid * NCH + c] = accL[nj][0];
        }
    }
}

// ---------------- combine split-K partials (bf16 partO -> bf16 attn) ----------------
__global__ __launch_bounds__(128) void combine(
    const short* __restrict__ partO, const float* __restrict__ partM,
    const float* __restrict__ partL, short* __restrict__ attnb)
{
    const int rowid = blockIdx.x;        // bh*256 + q
    const int bh = rowid >> 8, q = rowid & 255;
    const int b = bh / NH, h = bh % NH;
    const int d = threadIdx.x;

    float m[NCH];
    float M = -INFINITY;
    #pragma unroll
    for (int c = 0; c < NCH; ++c) { m[c] = partM[(size_t)rowid * NCH + c]; M = fmaxf(M, m[c]); }
    float L = 0.f, o = 0.f;
    #pragma unroll
    for (int c = 0; c < NCH; ++c) {
        float w = exp2f(m[c] - M);
        L += partL[(size_t)rowid * NCH + c] * w;
        unsigned ub = (unsigned)(unsigned short)partO[((size_t)rowid * NCH + c) * HD + d];
        float ov = __builtin_bit_cast(float, ub << 16);
        o += ov * w;
    }
    attnb[(size_t)(b * SN + q) * DM + h * HD + d] = bfc(o / L);
}

extern "C" void kernel_launch(void* const* d_in, const int* in_sizes, int n_in,
                              void* d_out, int out_size, void* d_ws, size_t ws_size,
                              hipStream_t stream) {
    const float* x      = (const float*)d_in[0];
    const float* freqs  = (const float*)d_in[1];
    const float* kcache = (const float*)d_in[2];
    const float* vcache = (const float*)d_in[3];
    const float* Wq = (const float*)d_in[4];
    const float* bq = (const float*)d_in[5];
    const float* Wk = (const float*)d_in[6];
    const float* bk = (const float*)d_in[7];
    const float* Wv = (const float*)d_in[8];
    const float* bv = (const float*)d_in[9];
    const float* Wo = (const float*)d_in[10];
    const float* bo = (const float*)d_in[11];
    const float* gq = (const float*)d_in[12];
    const float* gk = (const float*)d_in[13];
    float* out = (float*)d_out;

    auto al = [](size_t v) { return (v + 255) & ~(size_t)255; };
    const size_t SZ_QF  = (size_t)MR * DM * 4;
    const size_t SZ_QBF = (size_t)MR * DM * 2;
    const size_t SZ_PML = (size_t)48 * SN * NCH * 4;
    const size_t SZ_PO  = (size_t)48 * SN * NCH * HD * 2;   // bf16 partials

    char* ws = (char*)d_ws;
    float* qf    = (float*)ws; ws += al(SZ_QF);
    float* kfb   = (float*)ws; ws += al(SZ_QF);
    float* vfb   = (float*)ws; ws += al(SZ_QF);
    short* qbf   = (short*)ws; ws += al(SZ_QBF);
    short* xb    = (short*)ws; ws += al(SZ_QBF);
    short* attnb = (short*)ws; ws += al(SZ_QBF);
    float* pM    = (float*)ws; ws += al(SZ_PML);
    float* pL    = (float*)ws; ws += al(SZ_PML);
    short* pO    = (short*)ws; ws += al(SZ_PO);

    xcast<<<dim3(768), 256, 0, stream>>>(x, xb);
    gemm_bias<<<dim3(48, 4, 3), 256, 0, stream>>>(xb, Wq, Wk, Wv, bq, bk, bv, qf, kfb, vfb);
    norm_rope<<<dim3(1024), 256, 0, stream>>>(qf, kfb, qbf, gq, gk, freqs);
    attn_fa<<<dim3(432), 512, 0, stream>>>(qbf, kfb, vfb, kcache, vcache, pO, pM, pL);
    combine<<<dim3(12288), 128, 0, stream>>>(pO, pM, pL, attnb);
    gemm_bias<<<dim3(48, 4, 1), 256, 0, stream>>>(attnb, Wo, Wo, Wo, bo, bo, bo, out, out, out);
}